// Round 2
// baseline (983.091 us; speedup 1.0000x reference)
//
#include <hip/hip_runtime.h>
#include <hip/hip_bf16.h>
#include <stdint.h>

// ---------------------------------------------------------------------------
// GQA per-token head-mixing attention, MI355X (gfx950)
// Round 2: GEMMs ported to the 256x256 / BK=64 / 8-wave deep-pipelined
// template (T1 XCD swizzle + T2 LDS XOR swizzle + T3/T4 counted vmcnt phases
// + T5 setprio). rope_attn and converts unchanged from round 1.
// Workspace: xb (64MiB) | wqkv (24MiB) | wo (8MiB) | qkv (192MiB) = 288MiB.
// ---------------------------------------------------------------------------

typedef __attribute__((ext_vector_type(8))) short short8;
typedef __attribute__((ext_vector_type(4))) float f32x4;
typedef uint16_t u16;

typedef __attribute__((address_space(1))) const void as1_const_void;
typedef __attribute__((address_space(3))) void as3_void;

#define GLD_LDS16(gp, lp)                                                     \
  __builtin_amdgcn_global_load_lds((as1_const_void*)(gp), (as3_void*)(lp),    \
                                   16, 0, 0)

#define BAR() asm volatile("s_barrier" ::: "memory")
#define LGKM0()                                            \
  {                                                        \
    asm volatile("s_waitcnt lgkmcnt(0)" ::: "memory");     \
    __builtin_amdgcn_sched_barrier(0);                     \
  }
#define VMCNT(n) asm volatile("s_waitcnt vmcnt(" #n ")" ::: "memory")

__device__ __forceinline__ short8 ds_read_b128p(const char* p) {
  short8 r;
  const __attribute__((address_space(3))) char* lp =
      (const __attribute__((address_space(3))) char*)p;
  asm volatile("ds_read_b128 %0, %1" : "=v"(r) : "v"(lp));
  return r;
}

__device__ __forceinline__ float bf2f(u16 u) {
  uint32_t x = ((uint32_t)u) << 16;
  float f;
  __builtin_memcpy(&f, &x, 4);
  return f;
}
__device__ __forceinline__ u16 f2bf(float f) {
  uint32_t u;
  __builtin_memcpy(&u, &f, 4);
  u += 0x7fffu + ((u >> 16) & 1u);  // round-to-nearest-even
  return (u16)(u >> 16);
}

// ---------------- f32 -> bf16 convert, 4 elems/thread ----------------------
__global__ __launch_bounds__(256) void cvt_f32_to_bf16_v4(
    const float* __restrict__ s, u16* __restrict__ d, int n4) {
  int i = blockIdx.x * 256 + threadIdx.x;
  if (i >= n4) return;
  const float4 v = reinterpret_cast<const float4*>(s)[i];
  ushort4 o;
  o.x = f2bf(v.x);
  o.y = f2bf(v.y);
  o.z = f2bf(v.z);
  o.w = f2bf(v.w);
  reinterpret_cast<ushort4*>(d)[i] = o;
}

// ---------------- C = A @ B^T : 256x256 tile, BK=64, 8 waves (2Mx4N) -------
// LDS map (128 KiB dynamic): buf b in {0,1} at b*65536;
//   half 0 = B rows [n0, n0+128)   at +0
//   half 1 = B rows [n0+128, +256) at +16384
//   half 2 = A rows [m0, m0+128)   at +32768
//   half 3 = A rows [m0+128, +256) at +49152
// Each half-tile: [128 rows][64 bf16], 128 B/row, XOR-swizzled:
//   physical_byte = logical_byte ^ ((row & 7) << 4)   (involution)
// Staged with linear-dest global_load_lds + inverse-swizzled global source.
template <int OUT_F32>
__global__ __launch_bounds__(512, 2) void gemm256(
    const u16* __restrict__ A, const u16* __restrict__ B,
    void* __restrict__ Cout, int M, int N, int K) {
  extern __shared__ char smem[];
  const int tid = threadIdx.x;
  const int lane = tid & 63;
  const int wid = tid >> 6;
  const int wr = wid >> 2;  // 0..1  (M half)
  const int wc = wid & 3;   // 0..3  (N quarter)
  const int lr = lane & 15;
  const int kq = lane >> 4;  // 0..3

  // T1: bijective XCD-aware remap of the linear block id (m204 form).
  const int nwg = gridDim.x * gridDim.y;
  const int orig = blockIdx.y * gridDim.x + blockIdx.x;
  const int qq = nwg >> 3, rr = nwg & 7;
  const int xcd = orig & 7, loc = orig >> 3;
  const int wg =
      (xcd < rr ? xcd * (qq + 1) : rr * (qq + 1) + (xcd - rr) * qq) + loc;
  const int m0 = (wg / gridDim.x) * 256;
  const int n0 = (wg % gridDim.x) * 256;

  const int nt = K >> 6;

  auto stage = [&](int bsel, int hidx, int kt) {
    char* base = smem + bsel * 65536 + hidx * 16384;
    const u16* G = (hidx >= 2) ? A : B;
    const int rowbase = (hidx >= 2) ? (m0 + (hidx - 2) * 128) : (n0 + hidx * 128);
#pragma unroll
    for (int it = 0; it < 2; ++it) {
      const int o = it * 8192 + tid * 16;  // linear dest byte in half-tile
      const int row = o >> 7;
      const int lch = ((o >> 4) & 7) ^ (row & 7);  // inverse-swizzled src chunk
      GLD_LDS16(G + (size_t)(rowbase + row) * K + (size_t)kt * 64 + lch * 8,
                base + it * 8192 + wid * 1024);
    }
  };
  auto frag = [&](const char* half, int row, int kk) {
    const uint32_t L = (uint32_t)(row * 128 + (kk * 4 + kq) * 16);
    return ds_read_b128p(half + (L ^ (((uint32_t)row & 7) << 4)));
  };

  f32x4 acc[8][4];
#pragma unroll
  for (int i = 0; i < 8; ++i)
#pragma unroll
    for (int j = 0; j < 4; ++j) acc[i][j] = (f32x4){0.f, 0.f, 0.f, 0.f};

  // Prologue: tile 0 fully, tile 1 halves 0..2. Then drain to 6 outstanding.
  stage(0, 0, 0);
  stage(0, 1, 0);
  stage(0, 2, 0);
  stage(0, 3, 0);
  stage(1, 0, 1);
  stage(1, 1, 1);
  stage(1, 2, 1);
  VMCNT(6);  // tile 0 landed; H(1,0..2) in flight
  BAR();

  int cur = 0;
#pragma unroll 2
  for (int t = 0; t < nt; ++t, cur ^= 1) {
    const char* Ah = smem + cur * 65536 + 32768 + wr * 16384;
    const char* Bh = smem + cur * 65536 + (wc >> 1) * 16384;
    short8 a0[4][2], a1[4][2], b0[2][2], b1[2][2];

    // ---- ph1: read A m0-3 + B n0-1; stage H(t+1, A1); MFMA Q1 ----
#pragma unroll
    for (int f = 0; f < 4; ++f) {
      const int row = f * 16 + lr;
      a0[f][0] = frag(Ah, row, 0);
      a0[f][1] = frag(Ah, row, 1);
    }
#pragma unroll
    for (int j = 0; j < 2; ++j) {
      const int row = (wc & 1) * 64 + j * 16 + lr;
      b0[j][0] = frag(Bh, row, 0);
      b0[j][1] = frag(Bh, row, 1);
    }
    if (t + 1 < nt) stage(cur ^ 1, 3, t + 1);
    BAR();
    LGKM0();
    __builtin_amdgcn_s_setprio(1);
#pragma unroll
    for (int i = 0; i < 4; ++i)
#pragma unroll
      for (int j = 0; j < 2; ++j) {
        acc[i][j] = __builtin_amdgcn_mfma_f32_16x16x32_bf16(
            a0[i][0], b0[j][0], acc[i][j], 0, 0, 0);
        acc[i][j] = __builtin_amdgcn_mfma_f32_16x16x32_bf16(
            a0[i][1], b0[j][1], acc[i][j], 0, 0, 0);
      }
    __builtin_amdgcn_s_setprio(0);
    BAR();

    // ---- ph2: read A m4-7 + B n2-3; MFMA Q2 (a0 x b1) ----
#pragma unroll
    for (int f = 0; f < 4; ++f) {
      const int row = (4 + f) * 16 + lr;
      a1[f][0] = frag(Ah, row, 0);
      a1[f][1] = frag(Ah, row, 1);
    }
#pragma unroll
    for (int j = 0; j < 2; ++j) {
      const int row = (wc & 1) * 64 + (2 + j) * 16 + lr;
      b1[j][0] = frag(Bh, row, 0);
      b1[j][1] = frag(Bh, row, 1);
    }
    BAR();
    LGKM0();
    __builtin_amdgcn_s_setprio(1);
#pragma unroll
    for (int i = 0; i < 4; ++i)
#pragma unroll
      for (int j = 0; j < 2; ++j) {
        acc[i][2 + j] = __builtin_amdgcn_mfma_f32_16x16x32_bf16(
            a0[i][0], b1[j][0], acc[i][2 + j], 0, 0, 0);
        acc[i][2 + j] = __builtin_amdgcn_mfma_f32_16x16x32_bf16(
            a0[i][1], b1[j][1], acc[i][2 + j], 0, 0, 0);
      }
    __builtin_amdgcn_s_setprio(0);
    BAR();

    // ---- ph3: stage H(t+2, B0), H(t+2, B1); MFMA Q3 (a1 x b0) ----
    if (t + 2 < nt) {
      stage(cur, 0, t + 2);
      stage(cur, 1, t + 2);
    }
    __builtin_amdgcn_s_setprio(1);
#pragma unroll
    for (int i = 0; i < 4; ++i)
#pragma unroll
      for (int j = 0; j < 2; ++j) {
        acc[4 + i][j] = __builtin_amdgcn_mfma_f32_16x16x32_bf16(
            a1[i][0], b0[j][0], acc[4 + i][j], 0, 0, 0);
        acc[4 + i][j] = __builtin_amdgcn_mfma_f32_16x16x32_bf16(
            a1[i][1], b0[j][1], acc[4 + i][j], 0, 0, 0);
      }
    __builtin_amdgcn_s_setprio(0);
    BAR();

    // ---- ph4: stage H(t+2, A0); MFMA Q4 (a1 x b1); counted vmcnt ----
    if (t + 2 < nt) stage(cur, 2, t + 2);
    __builtin_amdgcn_s_setprio(1);
#pragma unroll
    for (int i = 0; i < 4; ++i)
#pragma unroll
      for (int j = 0; j < 2; ++j) {
        acc[4 + i][2 + j] = __builtin_amdgcn_mfma_f32_16x16x32_bf16(
            a1[i][0], b1[j][0], acc[4 + i][2 + j], 0, 0, 0);
        acc[4 + i][2 + j] = __builtin_amdgcn_mfma_f32_16x16x32_bf16(
            a1[i][1], b1[j][1], acc[4 + i][2 + j], 0, 0, 0);
      }
    __builtin_amdgcn_s_setprio(0);
    if (t + 2 < nt) {
      VMCNT(6);  // tile t+1 fully landed; H(t+2,0..2) stay in flight
    } else if (t + 1 < nt) {
      VMCNT(0);  // last prefetch (H(nt-1,A1)) must land
    }
    BAR();
  }

  // Epilogue. C/D layout: col = lane&15, row = (lane>>4)*4 + e.
  const int rb = m0 + wr * 128 + (kq << 2);
  const int cb = n0 + wc * 64 + lr;
  if (OUT_F32) {
    float* C = (float*)Cout;
#pragma unroll
    for (int i = 0; i < 8; ++i)
#pragma unroll
      for (int j = 0; j < 4; ++j)
#pragma unroll
        for (int e = 0; e < 4; ++e)
          C[(size_t)(rb + i * 16 + e) * N + (cb + j * 16)] = acc[i][j][e];
  } else {
    u16* C = (u16*)Cout;
#pragma unroll
    for (int i = 0; i < 8; ++i)
#pragma unroll
      for (int j = 0; j < 4; ++j)
#pragma unroll
        for (int e = 0; e < 4; ++e)
          C[(size_t)(rb + i * 16 + e) * N + (cb + j * 16)] =
              f2bf(acc[i][j][e]);
  }
}

// ---------------- RoPE + head-mix attention, one block per token -----------
__global__ __launch_bounds__(256) void rope_attn(
    const u16* __restrict__ qkv, u16* __restrict__ attn, int S) {
  __shared__ float cosv[64], sinv[64];
  __shared__ float sq[16][132];  // +4 pad: kills 16-way bank conflict on dot
  __shared__ float sk[16][132];
  __shared__ float sp[16][16];
  const int token = blockIdx.x;
  const int s = token & (S - 1);  // S = 4096 (pow2); position in sequence
  const int tid = threadIdx.x;
  const u16* base = qkv + (size_t)token * 6144;

  if (tid < 64) {
    const float inv = powf(10000.0f, -(float)tid * (1.0f / 64.0f));
    float sv, cv;
    sincosf((float)s * inv, &sv, &cv);
    cosv[tid] = cv;
    sinv[tid] = sv;
  }
  __syncthreads();

#pragma unroll
  for (int p = 0; p < 8; ++p) {
    const int idx = p * 256 + tid;  // 0..2047
    const int mat = idx >> 10;      // 0 = q, 1 = k
    const int rem = idx & 1023;
    const int h = rem >> 6;
    const int i = rem & 63;
    const u16* src = base + mat * 2048 + h * 128 + 2 * i;
    const float x1 = bf2f(src[0]);
    const float x2 = bf2f(src[1]);
    const float c = cosv[i], sn = sinv[i];
    float* dst = mat ? sk[h] : sq[h];
    dst[2 * i] = x1 * c - x2 * sn;
    dst[2 * i + 1] = x1 * sn + x2 * c;
  }
  __syncthreads();

  {
    const int h = tid >> 4;
    const int t = tid & 15;
    const int hp = ((h & 3) << 2) | (h >> 2);  // original head feeding new h
    float sc = 0.f;
#pragma unroll
    for (int d = 0; d < 128; ++d) sc += sq[hp][d] * sk[t][d];
    sc *= 0.08838834764831845f;  // 1/sqrt(128)
    float mx = sc;
#pragma unroll
    for (int o = 8; o; o >>= 1) mx = fmaxf(mx, __shfl_xor(mx, o, 16));
    const float e = __expf(sc - mx);
    float sum = e;
#pragma unroll
    for (int o = 8; o; o >>= 1) sum += __shfl_xor(sum, o, 16);
    sp[h][t] = e / sum;
  }
  __syncthreads();

  {
    const int h = tid >> 4;
    const int d0 = (tid & 15) * 8;
    const u16* vb = base + 4096;
    float o[8] = {0.f, 0.f, 0.f, 0.f, 0.f, 0.f, 0.f, 0.f};
#pragma unroll
    for (int t = 0; t < 16; ++t) {
      const float pr = sp[h][t];
      const short8 vv = *reinterpret_cast<const short8*>(vb + t * 128 + d0);
#pragma unroll
      for (int e = 0; e < 8; ++e) o[e] += pr * bf2f((u16)vv[e]);
    }
    short8 ov;
#pragma unroll
    for (int e = 0; e < 8; ++e) ov[e] = (short)f2bf(o[e]);
    *reinterpret_cast<short8*>(attn + (size_t)token * 2048 + h * 128 + d0) =
        ov;
  }
}

// ---------------------------------------------------------------------------
extern "C" void kernel_launch(void* const* d_in, const int* in_sizes, int n_in,
                              void* d_out, int out_size, void* d_ws,
                              size_t ws_size, hipStream_t stream) {
  (void)in_sizes;
  (void)n_in;
  (void)out_size;
  (void)ws_size;
  const float* x = (const float*)d_in[0];
  const float* Wq = (const float*)d_in[1];
  const float* Wk = (const float*)d_in[2];
  const float* Wv = (const float*)d_in[3];
  const float* Wo = (const float*)d_in[4];
  float* out = (float*)d_out;

  const int B = 4, S = 4096, D = 2048;
  const int M = B * S;  // 16384

  char* ws = (char*)d_ws;
  u16* xb = (u16*)ws;                          // M*D bf16; reused as attn
  u16* wqkv = (u16*)(ws + (size_t)M * D * 2);  // 3*D*D bf16
  u16* wo = (u16*)((char*)wqkv + (size_t)3 * D * D * 2);
  u16* qkv = (u16*)((char*)wo + (size_t)D * D * 2);  // M*3D bf16

  // 128 KiB dynamic LDS opt-in (deterministic host-side call; not a stream op)
  hipFuncSetAttribute(reinterpret_cast<const void*>(&gemm256<0>),
                      hipFuncAttributeMaxDynamicSharedMemorySize, 131072);
  hipFuncSetAttribute(reinterpret_cast<const void*>(&gemm256<1>),
                      hipFuncAttributeMaxDynamicSharedMemorySize, 131072);

  // bf16 conversions
  cvt_f32_to_bf16_v4<<<(M * D / 4 + 255) / 256, 256, 0, stream>>>(x, xb,
                                                                  M * D / 4);
  const int w4 = D * D / 4;
  cvt_f32_to_bf16_v4<<<(w4 + 255) / 256, 256, 0, stream>>>(Wq, wqkv, w4);
  cvt_f32_to_bf16_v4<<<(w4 + 255) / 256, 256, 0, stream>>>(
      Wk, wqkv + (size_t)D * D, w4);
  cvt_f32_to_bf16_v4<<<(w4 + 255) / 256, 256, 0, stream>>>(
      Wv, wqkv + (size_t)2 * D * D, w4);
  cvt_f32_to_bf16_v4<<<(w4 + 255) / 256, 256, 0, stream>>>(Wo, wo, w4);

  // qkv = x @ [Wq;Wk;Wv]^T   (M x 3D, bf16 out)
  gemm256<0><<<dim3(3 * D / 256, M / 256), 512, 131072, stream>>>(
      xb, wqkv, qkv, M, 3 * D, D);
  // RoPE + per-token head attention -> attn (reuses xb)
  rope_attn<<<M, 256, 0, stream>>>(qkv, xb, S);
  // out = attn @ Wo^T (f32 out)
  gemm256<1><<<dim3(D / 256, M / 256), 512, 131072, stream>>>(xb, wo, out, M,
                                                              D, D);
}

// Round 4
// 668.158 us; speedup vs baseline: 1.4713x; 1.4713x over previous
//
#include <hip/hip_runtime.h>
#include <hip/hip_bf16.h>
#include <stdint.h>

// ---------------------------------------------------------------------------
// GQA per-token head-mixing attention, MI355X (gfx950)
// Round 4: round-1 structure (128x128 tile, BK=64, 4 waves, compiler-managed
// syncs, 2-3 blocks/CU) + T2 LDS XOR swizzle (verified in round 2):
//   phys_byte = logical_byte ^ ((row & 7) << 4)
// applied as inverse-swizzled global SOURCE for linear-dest global_load_lds
// and swizzled address on the ds_read_b128 frag reads. Kills the 16-way
// bank conflict (1.5e8/dispatch in round 1). rope_attn/converts unchanged.
// ---------------------------------------------------------------------------

typedef __attribute__((ext_vector_type(8))) short short8;
typedef __attribute__((ext_vector_type(4))) float f32x4;
typedef uint16_t u16;

typedef __attribute__((address_space(1))) const void as1_const_void;
typedef __attribute__((address_space(3))) void as3_void;
#define GLD_LDS16(gp, lp)                                                     \
  __builtin_amdgcn_global_load_lds((as1_const_void*)(gp), (as3_void*)(lp),    \
                                   16, 0, 0)

__device__ __forceinline__ float bf2f(u16 u) {
  uint32_t x = ((uint32_t)u) << 16;
  float f;
  __builtin_memcpy(&f, &x, 4);
  return f;
}
__device__ __forceinline__ u16 f2bf(float f) {
  uint32_t u;
  __builtin_memcpy(&u, &f, 4);
  u += 0x7fffu + ((u >> 16) & 1u);  // round-to-nearest-even
  return (u16)(u >> 16);
}

// ---------------- f32 -> bf16 convert, 4 elems/thread ----------------------
__global__ __launch_bounds__(256) void cvt_f32_to_bf16_v4(
    const float* __restrict__ s, u16* __restrict__ d, int n4) {
  int i = blockIdx.x * 256 + threadIdx.x;
  if (i >= n4) return;
  const float4 v = reinterpret_cast<const float4*>(s)[i];
  ushort4 o;
  o.x = f2bf(v.x);
  o.y = f2bf(v.y);
  o.z = f2bf(v.z);
  o.w = f2bf(v.w);
  reinterpret_cast<ushort4*>(d)[i] = o;
}

// ---------------- C = A @ B^T : A (MxK) bf16, B (NxK) bf16 -----------------
// 128x128 tile, BK=64, 4 waves (2x2, each 64x64), 16x16x32 bf16 MFMA.
// Tiles [128][64] u16 in LDS, XOR-swizzled (see header comment).
template <int OUT_F32>
__global__ __launch_bounds__(256, 2) void gemm_bt(
    const u16* __restrict__ A, const u16* __restrict__ B,
    void* __restrict__ Cout, int M, int N, int K) {
  __shared__ u16 sA[128 * 64];
  __shared__ u16 sB[128 * 64];
  const int tid = threadIdx.x;
  const int lane = tid & 63;
  const int wid = tid >> 6;
  const int m0 = blockIdx.y * 128;
  const int n0 = blockIdx.x * 128;
  const int wr = wid >> 1, wc = wid & 1;
  const int lr = lane & 15;
  const int kq = lane >> 4;  // 0..3

  f32x4 acc[4][4];
#pragma unroll
  for (int i = 0; i < 4; ++i)
#pragma unroll
    for (int j = 0; j < 4; ++j) acc[i][j] = {0.f, 0.f, 0.f, 0.f};

  const int nK = K >> 6;  // K / 64
  for (int kt = 0; kt < nK; ++kt) {
    const u16* Ag = A + (size_t)m0 * K + kt * 64;
    const u16* Bg = B + (size_t)n0 * K + kt * 64;
    // Stage [128][64] tile: linear LDS dest (wave base + lane*16), global
    // source taken from the INVERSE-swizzled chunk so that a swizzled
    // ds_read sees logical data (verified pair, round 2).
#pragma unroll
    for (int it = 0; it < 4; ++it) {
      const int o = it * 4096 + tid * 16;            // dest byte in tile
      const int row = o >> 7;                        // 128 B per row
      const int lch = ((o >> 4) & 7) ^ (row & 7);    // src 16B-chunk index
      GLD_LDS16(Ag + (size_t)row * K + lch * 8,
                (char*)sA + it * 4096 + wid * 1024);
    }
#pragma unroll
    for (int it = 0; it < 4; ++it) {
      const int o = it * 4096 + tid * 16;
      const int row = o >> 7;
      const int lch = ((o >> 4) & 7) ^ (row & 7);
      GLD_LDS16(Bg + (size_t)row * K + lch * 8,
                (char*)sB + it * 4096 + wid * 1024);
    }
    __syncthreads();  // compiler emits vmcnt(0) drain before s_barrier

#pragma unroll
    for (int kk = 0; kk < 2; ++kk) {
      short8 af[4], bfr[4];
#pragma unroll
      for (int f = 0; f < 4; ++f) {
        const int ra = wr * 64 + f * 16 + lr;
        const uint32_t La = (uint32_t)(ra * 128 + kk * 64 + kq * 16);
        af[f] = *reinterpret_cast<const short8*>(
            (const char*)sA + (La ^ (((uint32_t)ra & 7) << 4)));
        const int rb = wc * 64 + f * 16 + lr;
        const uint32_t Lb = (uint32_t)(rb * 128 + kk * 64 + kq * 16);
        bfr[f] = *reinterpret_cast<const short8*>(
            (const char*)sB + (Lb ^ (((uint32_t)rb & 7) << 4)));
      }
#pragma unroll
      for (int i = 0; i < 4; ++i)
#pragma unroll
        for (int j = 0; j < 4; ++j)
          acc[i][j] = __builtin_amdgcn_mfma_f32_16x16x32_bf16(
              af[i], bfr[j], acc[i][j], 0, 0, 0);
    }
    __syncthreads();
  }

  // Epilogue. C/D layout: col = lane&15, row = (lane>>4)*4 + e  [m89/m91].
  const int rbase = m0 + wr * 64 + (kq << 2);
  const int cbase = n0 + wc * 64 + lr;
  if (OUT_F32) {
    float* C = (float*)Cout;
#pragma unroll
    for (int i = 0; i < 4; ++i)
#pragma unroll
      for (int j = 0; j < 4; ++j)
#pragma unroll
        for (int e = 0; e < 4; ++e)
          C[(size_t)(rbase + i * 16 + e) * N + (cbase + j * 16)] =
              acc[i][j][e];
  } else {
    u16* C = (u16*)Cout;
#pragma unroll
    for (int i = 0; i < 4; ++i)
#pragma unroll
      for (int j = 0; j < 4; ++j)
#pragma unroll
        for (int e = 0; e < 4; ++e)
          C[(size_t)(rbase + i * 16 + e) * N + (cbase + j * 16)] =
              f2bf(acc[i][j][e]);
  }
}

// ---------------- RoPE + head-mix attention, one block per token -----------
__global__ __launch_bounds__(256) void rope_attn(
    const u16* __restrict__ qkv, u16* __restrict__ attn, int S) {
  __shared__ float cosv[64], sinv[64];
  __shared__ float sq[16][132];  // +4 pad: kills 16-way bank conflict on dot
  __shared__ float sk[16][132];
  __shared__ float sp[16][16];
  const int token = blockIdx.x;
  const int s = token & (S - 1);  // S = 4096 (pow2); position in sequence
  const int tid = threadIdx.x;
  const u16* base = qkv + (size_t)token * 6144;

  if (tid < 64) {
    const float inv = powf(10000.0f, -(float)tid * (1.0f / 64.0f));
    float sv, cv;
    sincosf((float)s * inv, &sv, &cv);
    cosv[tid] = cv;
    sinv[tid] = sv;
  }
  __syncthreads();

#pragma unroll
  for (int p = 0; p < 8; ++p) {
    const int idx = p * 256 + tid;  // 0..2047
    const int mat = idx >> 10;      // 0 = q, 1 = k
    const int rem = idx & 1023;
    const int h = rem >> 6;
    const int i = rem & 63;
    const u16* src = base + mat * 2048 + h * 128 + 2 * i;
    const float x1 = bf2f(src[0]);
    const float x2 = bf2f(src[1]);
    const float c = cosv[i], sn = sinv[i];
    float* dst = mat ? sk[h] : sq[h];
    dst[2 * i] = x1 * c - x2 * sn;
    dst[2 * i + 1] = x1 * sn + x2 * c;
  }
  __syncthreads();

  {
    const int h = tid >> 4;
    const int t = tid & 15;
    const int hp = ((h & 3) << 2) | (h >> 2);  // original head feeding new h
    float sc = 0.f;
#pragma unroll
    for (int d = 0; d < 128; ++d) sc += sq[hp][d] * sk[t][d];
    sc *= 0.08838834764831845f;  // 1/sqrt(128)
    float mx = sc;
#pragma unroll
    for (int o = 8; o; o >>= 1) mx = fmaxf(mx, __shfl_xor(mx, o, 16));
    const float e = __expf(sc - mx);
    float sum = e;
#pragma unroll
    for (int o = 8; o; o >>= 1) sum += __shfl_xor(sum, o, 16);
    sp[h][t] = e / sum;
  }
  __syncthreads();

  {
    const int h = tid >> 4;
    const int d0 = (tid & 15) * 8;
    const u16* vb = base + 4096;
    float o[8] = {0.f, 0.f, 0.f, 0.f, 0.f, 0.f, 0.f, 0.f};
#pragma unroll
    for (int t = 0; t < 16; ++t) {
      const float pr = sp[h][t];
      const short8 vv = *reinterpret_cast<const short8*>(vb + t * 128 + d0);
#pragma unroll
      for (int e = 0; e < 8; ++e) o[e] += pr * bf2f((u16)vv[e]);
    }
    short8 ov;
#pragma unroll
    for (int e = 0; e < 8; ++e) ov[e] = (short)f2bf(o[e]);
    *reinterpret_cast<short8*>(attn + (size_t)token * 2048 + h * 128 + d0) =
        ov;
  }
}

// ---------------------------------------------------------------------------
extern "C" void kernel_launch(void* const* d_in, const int* in_sizes, int n_in,
                              void* d_out, int out_size, void* d_ws,
                              size_t ws_size, hipStream_t stream) {
  (void)in_sizes;
  (void)n_in;
  (void)out_size;
  (void)ws_size;
  const float* x = (const float*)d_in[0];
  const float* Wq = (const float*)d_in[1];
  const float* Wk = (const float*)d_in[2];
  const float* Wv = (const float*)d_in[3];
  const float* Wo = (const float*)d_in[4];
  float* out = (float*)d_out;

  const int B = 4, S = 4096, D = 2048;
  const int M = B * S;  // 16384

  char* ws = (char*)d_ws;
  u16* xb = (u16*)ws;                          // M*D bf16; reused as attn
  u16* wqkv = (u16*)(ws + (size_t)M * D * 2);  // 3*D*D bf16
  u16* wo = (u16*)((char*)wqkv + (size_t)3 * D * D * 2);
  u16* qkv = (u16*)((char*)wo + (size_t)D * D * 2);  // M*3D bf16

  // bf16 conversions
  cvt_f32_to_bf16_v4<<<(M * D / 4 + 255) / 256, 256, 0, stream>>>(x, xb,
                                                                  M * D / 4);
  const int w4 = D * D / 4;
  cvt_f32_to_bf16_v4<<<(w4 + 255) / 256, 256, 0, stream>>>(Wq, wqkv, w4);
  cvt_f32_to_bf16_v4<<<(w4 + 255) / 256, 256, 0, stream>>>(
      Wk, wqkv + (size_t)D * D, w4);
  cvt_f32_to_bf16_v4<<<(w4 + 255) / 256, 256, 0, stream>>>(
      Wv, wqkv + (size_t)2 * D * D, w4);
  cvt_f32_to_bf16_v4<<<(w4 + 255) / 256, 256, 0, stream>>>(Wo, wo, w4);

  // qkv = x @ [Wq;Wk;Wv]^T   (M x 3D, bf16 out)
  gemm_bt<0><<<dim3(3 * D / 128, M / 128), 256, 0, stream>>>(xb, wqkv, qkv, M,
                                                             3 * D, D);
  // RoPE + per-token head attention -> attn (reuses xb)
  rope_attn<<<M, 256, 0, stream>>>(qkv, xb, S);
  // out = attn @ Wo^T (f32 out)
  gemm_bt<1><<<dim3(D / 128, M / 128), 256, 0, stream>>>(xb, wo, out, M, D, D);
}

// Round 5
// 645.546 us; speedup vs baseline: 1.5229x; 1.0350x over previous
//
#include <hip/hip_runtime.h>
#include <hip/hip_bf16.h>
#include <stdint.h>

// ---------------------------------------------------------------------------
// GQA per-token head-mixing attention, MI355X (gfx950)
// Round 5: keep round-4's proven multi-block 2-phase structure + T2 swizzle,
// but grow the tile to 256(M)x128(N) with 4 waves of 128x64 output each
// (m201 per-wave intensity): LDS frag bytes/FLOP x0.73, staging bytes/FLOP
// x0.71 vs round 4. 48 KiB LDS/block, __launch_bounds__(256,2) keeps
// 2 blocks/CU of cross-block TLP. Swizzle pair (inverse-swizzled global
// source for linear-dest global_load_lds + swizzled ds_read) unchanged.
// rope_attn and converts unchanged.
// ---------------------------------------------------------------------------

typedef __attribute__((ext_vector_type(8))) short short8;
typedef __attribute__((ext_vector_type(4))) float f32x4;
typedef uint16_t u16;

typedef __attribute__((address_space(1))) const void as1_const_void;
typedef __attribute__((address_space(3))) void as3_void;
#define GLD_LDS16(gp, lp)                                                     \
  __builtin_amdgcn_global_load_lds((as1_const_void*)(gp), (as3_void*)(lp),    \
                                   16, 0, 0)

__device__ __forceinline__ float bf2f(u16 u) {
  uint32_t x = ((uint32_t)u) << 16;
  float f;
  __builtin_memcpy(&f, &x, 4);
  return f;
}
__device__ __forceinline__ u16 f2bf(float f) {
  uint32_t u;
  __builtin_memcpy(&u, &f, 4);
  u += 0x7fffu + ((u >> 16) & 1u);  // round-to-nearest-even
  return (u16)(u >> 16);
}

// ---------------- f32 -> bf16 convert, 4 elems/thread ----------------------
__global__ __launch_bounds__(256) void cvt_f32_to_bf16_v4(
    const float* __restrict__ s, u16* __restrict__ d, int n4) {
  int i = blockIdx.x * 256 + threadIdx.x;
  if (i >= n4) return;
  const float4 v = reinterpret_cast<const float4*>(s)[i];
  ushort4 o;
  o.x = f2bf(v.x);
  o.y = f2bf(v.y);
  o.z = f2bf(v.z);
  o.w = f2bf(v.w);
  reinterpret_cast<ushort4*>(d)[i] = o;
}

// ---------------- C = A @ B^T : A (MxK) bf16, B (NxK) bf16 -----------------
// 256x128 tile, BK=64, 4 waves (2M x 2N), each wave owns 128x64 of C.
// LDS tiles [rows][64] u16, 128 B/row, XOR swizzle:
//   phys_byte = logical_byte ^ ((row & 7) << 4)
// staged via linear-dest global_load_lds + inverse-swizzled global source.
template <int OUT_F32>
__global__ __launch_bounds__(256, 2) void gemm_bt(
    const u16* __restrict__ A, const u16* __restrict__ B,
    void* __restrict__ Cout, int M, int N, int K) {
  __shared__ u16 sA[256 * 64];  // 32 KiB
  __shared__ u16 sB[128 * 64];  // 16 KiB
  const int tid = threadIdx.x;
  const int lane = tid & 63;
  const int wid = tid >> 6;
  const int m0 = blockIdx.y * 256;
  const int n0 = blockIdx.x * 128;
  const int wr = wid >> 1, wc = wid & 1;  // wave -> (M half, N half)
  const int lr = lane & 15;
  const int kq = lane >> 4;  // 0..3

  f32x4 acc[8][4];
#pragma unroll
  for (int i = 0; i < 8; ++i)
#pragma unroll
    for (int j = 0; j < 4; ++j) acc[i][j] = {0.f, 0.f, 0.f, 0.f};

  const int nK = K >> 6;  // K / 64
  for (int kt = 0; kt < nK; ++kt) {
    const u16* Ag = A + (size_t)m0 * K + kt * 64;
    const u16* Bg = B + (size_t)n0 * K + kt * 64;
    // Stage A [256][64] (8 iters) and B [128][64] (4 iters); linear LDS dest
    // (wave base + lane*16), inverse-swizzled global source chunk.
#pragma unroll
    for (int it = 0; it < 8; ++it) {
      const int o = it * 4096 + tid * 16;          // dest byte in tile
      const int row = o >> 7;                      // 128 B per row
      const int lch = ((o >> 4) & 7) ^ (row & 7);  // src 16B-chunk index
      GLD_LDS16(Ag + (size_t)row * K + lch * 8,
                (char*)sA + it * 4096 + wid * 1024);
    }
#pragma unroll
    for (int it = 0; it < 4; ++it) {
      const int o = it * 4096 + tid * 16;
      const int row = o >> 7;
      const int lch = ((o >> 4) & 7) ^ (row & 7);
      GLD_LDS16(Bg + (size_t)row * K + lch * 8,
                (char*)sB + it * 4096 + wid * 1024);
    }
    __syncthreads();  // compiler emits vmcnt(0) drain before s_barrier

#pragma unroll
    for (int kk = 0; kk < 2; ++kk) {
      short8 af[8], bfr[4];
#pragma unroll
      for (int f = 0; f < 8; ++f) {
        const int ra = wr * 128 + f * 16 + lr;
        const uint32_t La = (uint32_t)(ra * 128 + kk * 64 + kq * 16);
        af[f] = *reinterpret_cast<const short8*>(
            (const char*)sA + (La ^ (((uint32_t)ra & 7) << 4)));
      }
#pragma unroll
      for (int f = 0; f < 4; ++f) {
        const int rb = wc * 64 + f * 16 + lr;
        const uint32_t Lb = (uint32_t)(rb * 128 + kk * 64 + kq * 16);
        bfr[f] = *reinterpret_cast<const short8*>(
            (const char*)sB + (Lb ^ (((uint32_t)rb & 7) << 4)));
      }
#pragma unroll
      for (int i = 0; i < 8; ++i)
#pragma unroll
        for (int j = 0; j < 4; ++j)
          acc[i][j] = __builtin_amdgcn_mfma_f32_16x16x32_bf16(
              af[i], bfr[j], acc[i][j], 0, 0, 0);
    }
    __syncthreads();
  }

  // Epilogue. C/D layout: col = lane&15, row = (lane>>4)*4 + e  [m89/m91].
  const int rbase = m0 + wr * 128 + (kq << 2);
  const int cbase = n0 + wc * 64 + lr;
  if (OUT_F32) {
    float* C = (float*)Cout;
#pragma unroll
    for (int i = 0; i < 8; ++i)
#pragma unroll
      for (int j = 0; j < 4; ++j)
#pragma unroll
        for (int e = 0; e < 4; ++e)
          C[(size_t)(rbase + i * 16 + e) * N + (cbase + j * 16)] =
              acc[i][j][e];
  } else {
    u16* C = (u16*)Cout;
#pragma unroll
    for (int i = 0; i < 8; ++i)
#pragma unroll
      for (int j = 0; j < 4; ++j)
#pragma unroll
        for (int e = 0; e < 4; ++e)
          C[(size_t)(rbase + i * 16 + e) * N + (cbase + j * 16)] =
              f2bf(acc[i][j][e]);
  }
}

// ---------------- RoPE + head-mix attention, one block per token -----------
__global__ __launch_bounds__(256) void rope_attn(
    const u16* __restrict__ qkv, u16* __restrict__ attn, int S) {
  __shared__ float cosv[64], sinv[64];
  __shared__ float sq[16][132];  // +4 pad: kills 16-way bank conflict on dot
  __shared__ float sk[16][132];
  __shared__ float sp[16][16];
  const int token = blockIdx.x;
  const int s = token & (S - 1);  // S = 4096 (pow2); position in sequence
  const int tid = threadIdx.x;
  const u16* base = qkv + (size_t)token * 6144;

  if (tid < 64) {
    const float inv = powf(10000.0f, -(float)tid * (1.0f / 64.0f));
    float sv, cv;
    sincosf((float)s * inv, &sv, &cv);
    cosv[tid] = cv;
    sinv[tid] = sv;
  }
  __syncthreads();

#pragma unroll
  for (int p = 0; p < 8; ++p) {
    const int idx = p * 256 + tid;  // 0..2047
    const int mat = idx >> 10;      // 0 = q, 1 = k
    const int rem = idx & 1023;
    const int h = rem >> 6;
    const int i = rem & 63;
    const u16* src = base + mat * 2048 + h * 128 + 2 * i;
    const float x1 = bf2f(src[0]);
    const float x2 = bf2f(src[1]);
    const float c = cosv[i], sn = sinv[i];
    float* dst = mat ? sk[h] : sq[h];
    dst[2 * i] = x1 * c - x2 * sn;
    dst[2 * i + 1] = x1 * sn + x2 * c;
  }
  __syncthreads();

  {
    const int h = tid >> 4;
    const int t = tid & 15;
    const int hp = ((h & 3) << 2) | (h >> 2);  // original head feeding new h
    float sc = 0.f;
#pragma unroll
    for (int d = 0; d < 128; ++d) sc += sq[hp][d] * sk[t][d];
    sc *= 0.08838834764831845f;  // 1/sqrt(128)
    float mx = sc;
#pragma unroll
    for (int o = 8; o; o >>= 1) mx = fmaxf(mx, __shfl_xor(mx, o, 16));
    const float e = __expf(sc - mx);
    float sum = e;
#pragma unroll
    for (int o = 8; o; o >>= 1) sum += __shfl_xor(sum, o, 16);
    sp[h][t] = e / sum;
  }
  __syncthreads();

  {
    const int h = tid >> 4;
    const int d0 = (tid & 15) * 8;
    const u16* vb = base + 4096;
    float o[8] = {0.f, 0.f, 0.f, 0.f, 0.f, 0.f, 0.f, 0.f};
#pragma unroll
    for (int t = 0; t < 16; ++t) {
      const float pr = sp[h][t];
      const short8 vv = *reinterpret_cast<const short8*>(vb + t * 128 + d0);
#pragma unroll
      for (int e = 0; e < 8; ++e) o[e] += pr * bf2f((u16)vv[e]);
    }
    short8 ov;
#pragma unroll
    for (int e = 0; e < 8; ++e) ov[e] = (short)f2bf(o[e]);
    *reinterpret_cast<short8*>(attn + (size_t)token * 2048 + h * 128 + d0) =
        ov;
  }
}

// ---------------------------------------------------------------------------
extern "C" void kernel_launch(void* const* d_in, const int* in_sizes, int n_in,
                              void* d_out, int out_size, void* d_ws,
                              size_t ws_size, hipStream_t stream) {
  (void)in_sizes;
  (void)n_in;
  (void)out_size;
  (void)ws_size;
  const float* x = (const float*)d_in[0];
  const float* Wq = (const float*)d_in[1];
  const float* Wk = (const float*)d_in[2];
  const float* Wv = (const float*)d_in[3];
  const float* Wo = (const float*)d_in[4];
  float* out = (float*)d_out;

  const int B = 4, S = 4096, D = 2048;
  const int M = B * S;  // 16384

  char* ws = (char*)d_ws;
  u16* xb = (u16*)ws;                          // M*D bf16; reused as attn
  u16* wqkv = (u16*)(ws + (size_t)M * D * 2);  // 3*D*D bf16
  u16* wo = (u16*)((char*)wqkv + (size_t)3 * D * D * 2);
  u16* qkv = (u16*)((char*)wo + (size_t)D * D * 2);  // M*3D bf16

  // bf16 conversions
  cvt_f32_to_bf16_v4<<<(M * D / 4 + 255) / 256, 256, 0, stream>>>(x, xb,
                                                                  M * D / 4);
  const int w4 = D * D / 4;
  cvt_f32_to_bf16_v4<<<(w4 + 255) / 256, 256, 0, stream>>>(Wq, wqkv, w4);
  cvt_f32_to_bf16_v4<<<(w4 + 255) / 256, 256, 0, stream>>>(
      Wk, wqkv + (size_t)D * D, w4);
  cvt_f32_to_bf16_v4<<<(w4 + 255) / 256, 256, 0, stream>>>(
      Wv, wqkv + (size_t)2 * D * D, w4);
  cvt_f32_to_bf16_v4<<<(w4 + 255) / 256, 256, 0, stream>>>(Wo, wo, w4);

  // qkv = x @ [Wq;Wk;Wv]^T   (M x 3D, bf16 out)
  gemm_bt<0><<<dim3(3 * D / 128, M / 256), 256, 0, stream>>>(xb, wqkv, qkv, M,
                                                             3 * D, D);
  // RoPE + per-token head attention -> attn (reuses xb)
  rope_attn<<<M, 256, 0, stream>>>(qkv, xb, S);
  // out = attn @ Wo^T (f32 out)
  gemm_bt<1><<<dim3(D / 128, M / 256), 256, 0, stream>>>(xb, wo, out, M, D, D);
}